// Round 1
// 721.336 us; speedup vs baseline: 1.0222x; 1.0222x over previous
//
#include <hip/hip_runtime.h>
#include <hip/hip_bf16.h>

// B=32, S=577, H=1024, NH=16, DH=64. fp32 inputs / fp32 OUTPUT.
// Round 7: flash_attn latency attack. Counters showed MfmaUtil 7.4% / HBM 17%
// / VALU 31% => latency-bound. Changes: (1) swapped QK^T (mfma(K,Q)) so each
// lane holds P[q=l16][k=quad*4+r] -> packed b64 P-writes, per-lane scalar
// row-sum; (2) sched_barriers removed, K double-buffered in regs, V loads
// issued first (software pipeline); (3) mask staged in LDS per block;
// (4) XCD-aware 1-D grid swizzle co-locating each (b,h)'s 10 blocks on one
// XCD (K/V become L2-resident). GEMMs unchanged (m97, L3-fit => no swizzle).

typedef __bf16 bf16_t;
typedef __bf16 bf16x8 __attribute__((ext_vector_type(8)));
typedef __bf16 bf16x4 __attribute__((ext_vector_type(4)));
typedef float f32x4 __attribute__((ext_vector_type(4)));

#define B_   32
#define S_   577
#define SP   608
#define H_   1024
#define NH_  16
#define DH_  64
#define M_   (B_ * S_)    // 18464

typedef __attribute__((address_space(3))) unsigned int lds_u32;
typedef const __attribute__((address_space(1))) unsigned int glb_u32;
#define STAGE16(gp, lp) __builtin_amdgcn_global_load_lds((glb_u32*)(gp), (lds_u32*)(lp), 16, 0, 0)

__device__ __forceinline__ bf16x8 load8(const bf16_t* p) {
    return *reinterpret_cast<const bf16x8*>(p);
}
__device__ __forceinline__ bf16x8 load8f(const float* p) {
    f32x4 a = *reinterpret_cast<const f32x4*>(p);
    f32x4 b = *reinterpret_cast<const f32x4*>(p + 4);
    bf16x8 r;
    r[0] = (bf16_t)a[0]; r[1] = (bf16_t)a[1]; r[2] = (bf16_t)a[2]; r[3] = (bf16_t)a[3];
    r[4] = (bf16_t)b[0]; r[5] = (bf16_t)b[1]; r[6] = (bf16_t)b[2]; r[7] = (bf16_t)b[3];
    return r;
}

// ---------------- fp32 -> bf16 convert ----------------
__global__ __launch_bounds__(256) void cvt_f32_bf16(const float* __restrict__ src,
                                                    bf16_t* __restrict__ dst, int n8)
{
    int i = blockIdx.x * blockDim.x + threadIdx.x;
    const int stride = gridDim.x * blockDim.x;
    for (; i < n8; i += stride)
        *reinterpret_cast<bf16x8*>(dst + (size_t)i * 8) = load8f(src + (size_t)i * 8);
}

// all four weights in one launch; dsts are contiguous (Wqb..Wob in ws).
__global__ __launch_bounds__(256) void cvt_w4(
    const float* __restrict__ s0, const float* __restrict__ s1,
    const float* __restrict__ s2, const float* __restrict__ s3,
    bf16_t* __restrict__ dst)
{
    const int i = blockIdx.x * blockDim.x + threadIdx.x;   // 0..524287 (4*131072)
    const int which = i >> 17;                             // uniform per block
    const int off = i & ((1 << 17) - 1);
    const float* s = (which == 0) ? s0 : (which == 1) ? s1 : (which == 2) ? s2 : s3;
    *reinterpret_cast<bf16x8*>(dst + (size_t)i * 8) = load8f(s + (size_t)off * 8);
}

// ---------------- fused QKV projection, m97 structure ----------------
// grid (145, 24), block 256. Q outputs pre-scaled by 1/8 (=1/sqrt(DH)).
__global__ __launch_bounds__(256) void qkv_gemm(
    const bf16_t* __restrict__ Xb,
    const bf16_t* __restrict__ Wqb, const bf16_t* __restrict__ Wkb, const bf16_t* __restrict__ Wvb,
    const float* __restrict__ bq, const float* __restrict__ bk, const float* __restrict__ bv,
    bf16_t* __restrict__ Qb, bf16_t* __restrict__ Kb, bf16_t* __restrict__ VTb)
{
    __shared__ bf16_t smem[8192];          // A[128][32] | B[128][32], contiguous (no pad!)
    bf16_t* sA = smem;
    bf16_t* sB = smem + 4096;
    const int tid  = threadIdx.x;
    const int w    = tid >> 6, lane = tid & 63;
    const int quad = lane >> 4, l16 = lane & 15;
    const int wm = w & 1, wn = w >> 1;
    const int m0 = blockIdx.x * 128, n0 = blockIdx.y * 128;
    const int which = n0 >> 10;            // 128-tile never straddles a weight boundary
    const int nrel0 = n0 & 1023;
    const bf16_t* Wb   = (which == 0) ? Wqb : (which == 1) ? Wkb : Wvb;
    const float*  bias = (which == 0) ? bq  : (which == 1) ? bk  : bv;
    const float   oscale = (which == 0) ? 0.125f : 1.0f;

    const int f0 = tid, f1 = 256 + tid;
    const int rA0 = f0 >> 2, cA0 = (f0 & 3) * 8;
    const int rA1 = f1 >> 2, cA1 = (f1 & 3) * 8;
    int ga0 = m0 + rA0; if (ga0 > M_ - 1) ga0 = M_ - 1;
    int ga1 = m0 + rA1; if (ga1 > M_ - 1) ga1 = M_ - 1;
    const bf16_t* pA0 = Xb + (size_t)ga0 * H_ + cA0;
    const bf16_t* pA1 = Xb + (size_t)ga1 * H_ + cA1;
    const bf16_t* pB0 = Wb + (size_t)(nrel0 + rA0) * H_ + cA0;
    const bf16_t* pB1 = Wb + (size_t)(nrel0 + rA1) * H_ + cA1;
    bf16_t* lA0 = sA + w * 512;            // wave-uniform bases (+lane*16B by HW)
    bf16_t* lA1 = sA + 2048 + w * 512;
    bf16_t* lB0 = sB + w * 512;
    bf16_t* lB1 = sB + 2048 + w * 512;

    f32x4 acc[4][4] = {};
    for (int k0 = 0; k0 < H_; k0 += 32) {
        STAGE16(pA0 + k0, lA0);
        STAGE16(pA1 + k0, lA1);
        STAGE16(pB0 + k0, lB0);
        STAGE16(pB1 + k0, lB1);
        __syncthreads();
        bf16x8 af[4], bfv[4];
#pragma unroll
        for (int t = 0; t < 4; ++t) {
            af[t]  = load8(sA + (wm * 64 + t * 16 + l16) * 32 + quad * 8);
            bfv[t] = load8(sB + (wn * 64 + t * 16 + l16) * 32 + quad * 8);
        }
#pragma unroll
        for (int i = 0; i < 4; ++i)
#pragma unroll
            for (int j = 0; j < 4; ++j)
                acc[i][j] = __builtin_amdgcn_mfma_f32_16x16x32_bf16(af[i], bfv[j], acc[i][j], 0, 0, 0);
        __syncthreads();
    }

#pragma unroll
    for (int j = 0; j < 4; ++j) {
        const int nrel = nrel0 + wn * 64 + j * 16 + l16;
        const float bv_ = bias[nrel];
        const int h = nrel >> 6, d = nrel & 63;
#pragma unroll
        for (int i = 0; i < 4; ++i) {
#pragma unroll
            for (int r = 0; r < 4; ++r) {
                const int m = m0 + wm * 64 + i * 16 + quad * 4 + r;
                if (m >= M_) continue;
                const float val = (acc[i][j][r] + bv_) * oscale;
                const int b = m / S_, s = m - b * S_;
                const int bh = b * NH_ + h;
                if (which == 0)      Qb [((size_t)bh * S_ + s) * DH_ + d] = (bf16_t)val;
                else if (which == 1) Kb [((size_t)bh * S_ + s) * DH_ + d] = (bf16_t)val;
                else                 VTb[((size_t)bh * DH_ + d) * SP + s] = (bf16_t)val;
            }
        }
    }
}

// ---------------- flash attention, round 7 ----------------
// grid (5120), block 256 (4 waves, one 16-row q-tile each). 1-D grid with
// XCD swizzle: bid%8 = XCD -> works [xcd*640, xcd*640+640) -> each (b,h)'s
// 10 blocks co-resident on one XCD (K/V ~152KB stays in that XCD's L2).
// Swapped QK^T: s = mfma(K,Q) gives lane(l16,quad) reg r = P[q=l16][k=q*4+r]
// (C layout col=lane&15=q, row=quad*4+r=k). P then packs as 2x ds_write_b64
// per 32-k tile; A-frag for PV read back as one b128 (16B-granule XOR
// swizzle on l16&3 for banks). Row-sum l is a per-lane scalar, reduced once
// at the end over quads (shfl_xor 16,32). K double-buffered in registers;
// V loads issued at the top of each iteration; no sched_barriers -> the
// compiler pipelines loads across the exp/LDS chain.
__global__ __launch_bounds__(256, 4) void flash_attn(
    const bf16_t* __restrict__ Qb, const bf16_t* __restrict__ Kb,
    const bf16_t* __restrict__ VTb, const float* __restrict__ maskp,
    bf16_t* __restrict__ Ctx)
{
    __shared__ __align__(16) float  smask[SP];      // 2432B, zero-padded tail
    __shared__ __align__(16) bf16_t pld[4 * 512];   // 1KB per wave (P tile 16x32)
    const int tid  = threadIdx.x;
    const int w    = tid >> 6, lane = tid & 63;
    const int quad = lane >> 4, l16 = lane & 15;

    const int bid  = blockIdx.x;
    const int work = (bid & 7) * 640 + (bid >> 3);  // bijective, XCD-contiguous
    const int bh   = work / 10;
    const int qx   = work - bh * 10;
    const int b    = bh >> 4, h = bh & 15;

    for (int i = tid; i < SP; i += 256)
        smask[i] = (i < S_) ? maskp[b * S_ + i] : 0.f;
    __syncthreads();

    int qt = qx * 4 + w; if (qt > 36) qt = 36;      // dup work, same values
    const int q0 = qt * 16;

    const bf16_t* Qh = Qb  + (size_t)bh * S_ * DH_;
    const bf16_t* Kh = Kb  + (size_t)bh * S_ * DH_;
    const bf16_t* Vh = VTb + (size_t)bh * DH_ * SP;
    bf16_t* pw = pld + w * 512;

    int rowQ = q0 + l16; if (rowQ > S_ - 1) rowQ = S_ - 1;
    const bf16x8 aq0 = load8(Qh + rowQ * DH_ + quad * 8);
    const bf16x8 aq1 = load8(Qh + rowQ * DH_ + 32 + quad * 8);

    f32x4 o[4] = {};
    float lp = 0.f;

    // P-tile LDS layout: row q=l16 (32 bf16 = 8 chunks of 8B), 16B-granule
    // XOR swizzle g^=(l16&3). Writer chunk quad (tile0) / 4+quad (tile1);
    // reader b128 at granule quad. Bijective per row, read matches write.
    const int wrel0 = l16 * 32 + (((quad >> 1) ^ (l16 & 3)) * 8) + (quad & 1) * 4;
    const int wrel1 = l16 * 32 + ((((quad >> 1) + 2) ^ (l16 & 3)) * 8) + (quad & 1) * 4;
    const int rrel  = l16 * 32 + ((quad ^ (l16 & 3)) * 8);

    bf16x8 ka[4], kb_[4];
    ka[0] = load8(Kh + (l16)      * DH_ + quad * 8);
    ka[1] = load8(Kh + (l16)      * DH_ + 32 + quad * 8);
    ka[2] = load8(Kh + (16 + l16) * DH_ + quad * 8);
    ka[3] = load8(Kh + (16 + l16) * DH_ + 32 + quad * 8);

    auto body = [&](bf16x8 (&KC)[4], bf16x8 (&KN)[4], const int j0, const bool pf) {
        // V for this tile + K for next tile: issue before the compute chain.
        bf16x8 v0 = load8(Vh + (l16)      * SP + j0 + quad * 8);
        bf16x8 v1 = load8(Vh + (16 + l16) * SP + j0 + quad * 8);
        bf16x8 v2 = load8(Vh + (32 + l16) * SP + j0 + quad * 8);
        bf16x8 v3 = load8(Vh + (48 + l16) * SP + j0 + quad * 8);
        if (pf) {
            int a0 = j0 + 32 + l16; if (a0 > S_ - 1) a0 = S_ - 1;
            int a1 = j0 + 48 + l16; if (a1 > S_ - 1) a1 = S_ - 1;
            KN[0] = load8(Kh + a0 * DH_ + quad * 8);
            KN[1] = load8(Kh + a0 * DH_ + 32 + quad * 8);
            KN[2] = load8(Kh + a1 * DH_ + quad * 8);
            KN[3] = load8(Kh + a1 * DH_ + 32 + quad * 8);
        }
        // swapped QK^T: C[m=k][n=q] -> lane holds P-row slice of its q=l16
        f32x4 s0 = {}, s1 = {};
        s0 = __builtin_amdgcn_mfma_f32_16x16x32_bf16(KC[0], aq0, s0, 0, 0, 0);
        s0 = __builtin_amdgcn_mfma_f32_16x16x32_bf16(KC[1], aq1, s0, 0, 0, 0);
        s1 = __builtin_amdgcn_mfma_f32_16x16x32_bf16(KC[2], aq0, s1, 0, 0, 0);
        s1 = __builtin_amdgcn_mfma_f32_16x16x32_bf16(KC[3], aq1, s1, 0, 0, 0);
        const f32x4 mk0 = *reinterpret_cast<const f32x4*>(&smask[j0 + quad * 4]);
        const f32x4 mk1 = *reinterpret_cast<const f32x4*>(&smask[j0 + 16 + quad * 4]);
        bf16x4 p0, p1;
#pragma unroll
        for (int r = 0; r < 4; ++r) {
            const int c0 = j0 + quad * 4 + r;
            const float e0 = (c0      < S_) ? __expf(s0[r] * mk0[r]) : 0.f;
            const float e1 = (c0 + 16 < S_) ? __expf(s1[r] * mk1[r]) : 0.f;
            lp += e0 + e1;                      // P=0 on pad cols kills V poison
            p0[r] = (bf16_t)e0;
            p1[r] = (bf16_t)e1;
        }
        *reinterpret_cast<bf16x4*>(pw + wrel0) = p0;
        *reinterpret_cast<bf16x4*>(pw + wrel1) = p1;
        const bf16x8 ap = load8(pw + rrel);     // compiler orders via lgkmcnt
        o[0] = __builtin_amdgcn_mfma_f32_16x16x32_bf16(ap, v0, o[0], 0, 0, 0);
        o[1] = __builtin_amdgcn_mfma_f32_16x16x32_bf16(ap, v1, o[1], 0, 0, 0);
        o[2] = __builtin_amdgcn_mfma_f32_16x16x32_bf16(ap, v2, o[2], 0, 0, 0);
        o[3] = __builtin_amdgcn_mfma_f32_16x16x32_bf16(ap, v3, o[3], 0, 0, 0);
    };

    for (int j0 = 0; j0 < S_; j0 += 64) {       // 19 tiles: ka/kb alternate
        body(ka, kb_, j0, j0 + 32 < S_);
        if (j0 + 32 < S_) body(kb_, ka, j0 + 32, j0 + 64 < S_);
    }

    // full row-sum: lane has partial over its quad's k; reduce over quads.
    float lsum = lp;
    lsum += __shfl_xor(lsum, 16);
    lsum += __shfl_xor(lsum, 32);
    float linv[4];
#pragma unroll
    for (int r = 0; r < 4; ++r) linv[r] = 1.0f / __shfl(lsum, quad * 4 + r);

#pragma unroll
    for (int t = 0; t < 4; ++t) {
#pragma unroll
        for (int r = 0; r < 4; ++r) {
            const int s = q0 + quad * 4 + r;
            if (s < S_)
                Ctx[((size_t)(b * S_ + s) * NH_ + h) * DH_ + t * 16 + l16] =
                    (bf16_t)(o[t][r] * linv[r]);
        }
    }
}

// ---------------- output projection, m97 structure. FP32 out ----------------
// grid (145, 8), block 256
__global__ __launch_bounds__(256) void out_gemm(
    const bf16_t* __restrict__ Ctx, const bf16_t* __restrict__ Wob,
    const float* __restrict__ bo, float* __restrict__ Out)
{
    __shared__ bf16_t smem[8192];
    bf16_t* sA = smem;
    bf16_t* sB = smem + 4096;
    const int tid  = threadIdx.x;
    const int w    = tid >> 6, lane = tid & 63;
    const int quad = lane >> 4, l16 = lane & 15;
    const int wm = w & 1, wn = w >> 1;
    const int m0 = blockIdx.x * 128, n0 = blockIdx.y * 128;

    const int f0 = tid, f1 = 256 + tid;
    const int rA0 = f0 >> 2, cA0 = (f0 & 3) * 8;
    const int rA1 = f1 >> 2, cA1 = (f1 & 3) * 8;
    int ga0 = m0 + rA0; if (ga0 > M_ - 1) ga0 = M_ - 1;
    int ga1 = m0 + rA1; if (ga1 > M_ - 1) ga1 = M_ - 1;
    const bf16_t* pA0 = Ctx + (size_t)ga0 * H_ + cA0;
    const bf16_t* pA1 = Ctx + (size_t)ga1 * H_ + cA1;
    const bf16_t* pB0 = Wob + (size_t)(n0 + rA0) * H_ + cA0;
    const bf16_t* pB1 = Wob + (size_t)(n0 + rA1) * H_ + cA1;
    bf16_t* lA0 = sA + w * 512;
    bf16_t* lA1 = sA + 2048 + w * 512;
    bf16_t* lB0 = sB + w * 512;
    bf16_t* lB1 = sB + 2048 + w * 512;

    f32x4 acc[4][4] = {};
    for (int k0 = 0; k0 < H_; k0 += 32) {
        STAGE16(pA0 + k0, lA0);
        STAGE16(pA1 + k0, lA1);
        STAGE16(pB0 + k0, lB0);
        STAGE16(pB1 + k0, lB1);
        __syncthreads();
        bf16x8 af[4], bfv[4];
#pragma unroll
        for (int t = 0; t < 4; ++t) {
            af[t]  = load8(sA + (wm * 64 + t * 16 + l16) * 32 + quad * 8);
            bfv[t] = load8(sB + (wn * 64 + t * 16 + l16) * 32 + quad * 8);
        }
#pragma unroll
        for (int i = 0; i < 4; ++i)
#pragma unroll
            for (int j = 0; j < 4; ++j)
                acc[i][j] = __builtin_amdgcn_mfma_f32_16x16x32_bf16(af[i], bfv[j], acc[i][j], 0, 0, 0);
        __syncthreads();
    }

#pragma unroll
    for (int j = 0; j < 4; ++j) {
        const int n = n0 + wn * 64 + j * 16 + l16;
        const float bv_ = bo[n];
#pragma unroll
        for (int i = 0; i < 4; ++i) {
#pragma unroll
            for (int r = 0; r < 4; ++r) {
                const int m = m0 + wm * 64 + i * 16 + quad * 4 + r;
                if (m >= M_) continue;
                Out[(size_t)m * H_ + n] = acc[i][j][r] + bv_;
            }
        }
    }
}

extern "C" void kernel_launch(void* const* d_in, const int* in_sizes, int n_in,
                              void* d_out, int out_size, void* d_ws, size_t ws_size,
                              hipStream_t stream) {
    const float* hidden = (const float*)d_in[0];
    const float* mask   = (const float*)d_in[1];
    const float* Wq = (const float*)d_in[2];
    const float* bq = (const float*)d_in[3];
    const float* Wk = (const float*)d_in[4];
    const float* bk = (const float*)d_in[5];
    const float* Wv = (const float*)d_in[6];
    const float* bv = (const float*)d_in[7];
    const float* Wo = (const float*)d_in[8];
    const float* bo = (const float*)d_in[9];
    float* out = (float*)d_out;

    const size_t QK_EL = (size_t)B_ * NH_ * S_ * DH_;   // 18,907,136
    const size_t VT_EL = (size_t)B_ * NH_ * SP * DH_;   // 19,922,944
    const size_t X_EL  = (size_t)M_ * H_;               // 18,907,136
    const size_t W_EL  = (size_t)H_ * H_;               // 1,048,576
    const size_t NEED  = (2 * QK_EL + VT_EL + X_EL + 4 * W_EL) * sizeof(bf16_t); // ~161.7 MB
    if (ws_size < NEED) {
        hipMemsetAsync(d_out, 0, (size_t)out_size * sizeof(float), stream);
        return;
    }

    bf16_t* ws    = (bf16_t*)d_ws;
    bf16_t* Qb    = ws;
    bf16_t* Kb    = Qb + QK_EL;
    bf16_t* VTb   = Kb + QK_EL;
    bf16_t* XbCtx = VTb + VT_EL;      // X_bf16 during qkv; Ctx afterwards
    bf16_t* Wqb   = XbCtx + X_EL;
    bf16_t* Wkb   = Wqb + W_EL;
    bf16_t* Wvb   = Wkb + W_EL;
    bf16_t* Wob   = Wvb + W_EL;

    cvt_f32_bf16<<<2048, 256, 0, stream>>>(hidden, XbCtx, (int)(X_EL / 8));
    cvt_w4<<<2048, 256, 0, stream>>>(Wq, Wk, Wv, Wo, Wqb);   // Wqb..Wob contiguous

    dim3 g1((M_ + 127) / 128, (3 * H_) / 128);   // 145 x 24
    qkv_gemm<<<g1, dim3(256), 0, stream>>>(XbCtx, Wqb, Wkb, Wvb, bq, bk, bv, Qb, Kb, VTb);

    flash_attn<<<dim3(5120), dim3(256), 0, stream>>>(Qb, Kb, VTb, mask, XbCtx);  // Ctx aliases Xb

    dim3 g3((M_ + 127) / 128, H_ / 128);         // 145 x 8
    out_gemm<<<g3, dim3(256), 0, stream>>>(XbCtx, Wob, bo, out);
}

// Round 2
// 602.036 us; speedup vs baseline: 1.2248x; 1.1982x over previous
//
#include <hip/hip_runtime.h>
#include <hip/hip_bf16.h>

// B=32, S=577, H=1024, NH=16, DH=64. fp32 inputs / fp32 OUTPUT.
// Round 8: zero-shuffle flash_attn. R7 showed latency-bound (MFMA 7.6%, HBM
// 4.4%, VALU 23%): the P-tile LDS round-trip (write+lgkmcnt+read, 10.9M bank
// conflicts) and per-wave load chains dominate. Fix: permute K rows fed to
// the swapped QK^T (g0(m)=8(m>>2)+(m&3), second mfma +4) so lane (l16,quad)
// ends up holding P[q=l16][k=8q..8q+7] — exactly its own PV A-fragment. P
// stays in registers: exp -> cvt -> mfma, zero LDS, zero shuffles. Also: 2
// q-tiles per wave (K/V frags shared, 2x MFMA per load), K double-buffered
// in regs, launch_bounds(256,3) so the pipeline isn't register-collapsed.
// GEMMs unchanged (m97).

typedef __bf16 bf16_t;
typedef __bf16 bf16x8 __attribute__((ext_vector_type(8)));
typedef float f32x4 __attribute__((ext_vector_type(4)));

#define B_   32
#define S_   577
#define SP   608
#define H_   1024
#define NH_  16
#define DH_  64
#define M_   (B_ * S_)    // 18464

typedef __attribute__((address_space(3))) unsigned int lds_u32;
typedef const __attribute__((address_space(1))) unsigned int glb_u32;
#define STAGE16(gp, lp) __builtin_amdgcn_global_load_lds((glb_u32*)(gp), (lds_u32*)(lp), 16, 0, 0)

__device__ __forceinline__ bf16x8 load8(const bf16_t* p) {
    return *reinterpret_cast<const bf16x8*>(p);
}
__device__ __forceinline__ bf16x8 load8f(const float* p) {
    f32x4 a = *reinterpret_cast<const f32x4*>(p);
    f32x4 b = *reinterpret_cast<const f32x4*>(p + 4);
    bf16x8 r;
    r[0] = (bf16_t)a[0]; r[1] = (bf16_t)a[1]; r[2] = (bf16_t)a[2]; r[3] = (bf16_t)a[3];
    r[4] = (bf16_t)b[0]; r[5] = (bf16_t)b[1]; r[6] = (bf16_t)b[2]; r[7] = (bf16_t)b[3];
    return r;
}

// ---------------- fp32 -> bf16 convert ----------------
__global__ __launch_bounds__(256) void cvt_f32_bf16(const float* __restrict__ src,
                                                    bf16_t* __restrict__ dst, int n8)
{
    int i = blockIdx.x * blockDim.x + threadIdx.x;
    const int stride = gridDim.x * blockDim.x;
    for (; i < n8; i += stride)
        *reinterpret_cast<bf16x8*>(dst + (size_t)i * 8) = load8f(src + (size_t)i * 8);
}

// all four weights in one launch; dsts are contiguous (Wqb..Wob in ws).
__global__ __launch_bounds__(256) void cvt_w4(
    const float* __restrict__ s0, const float* __restrict__ s1,
    const float* __restrict__ s2, const float* __restrict__ s3,
    bf16_t* __restrict__ dst)
{
    const int i = blockIdx.x * blockDim.x + threadIdx.x;   // 0..524287 (4*131072)
    const int which = i >> 17;                             // uniform per block
    const int off = i & ((1 << 17) - 1);
    const float* s = (which == 0) ? s0 : (which == 1) ? s1 : (which == 2) ? s2 : s3;
    *reinterpret_cast<bf16x8*>(dst + (size_t)i * 8) = load8f(s + (size_t)off * 8);
}

// ---------------- fused QKV projection, m97 structure ----------------
// grid (145, 24), block 256. Q outputs pre-scaled by 1/8 (=1/sqrt(DH)).
__global__ __launch_bounds__(256) void qkv_gemm(
    const bf16_t* __restrict__ Xb,
    const bf16_t* __restrict__ Wqb, const bf16_t* __restrict__ Wkb, const bf16_t* __restrict__ Wvb,
    const float* __restrict__ bq, const float* __restrict__ bk, const float* __restrict__ bv,
    bf16_t* __restrict__ Qb, bf16_t* __restrict__ Kb, bf16_t* __restrict__ VTb)
{
    __shared__ bf16_t smem[8192];          // A[128][32] | B[128][32], contiguous (no pad!)
    bf16_t* sA = smem;
    bf16_t* sB = smem + 4096;
    const int tid  = threadIdx.x;
    const int w    = tid >> 6, lane = tid & 63;
    const int quad = lane >> 4, l16 = lane & 15;
    const int wm = w & 1, wn = w >> 1;
    const int m0 = blockIdx.x * 128, n0 = blockIdx.y * 128;
    const int which = n0 >> 10;            // 128-tile never straddles a weight boundary
    const int nrel0 = n0 & 1023;
    const bf16_t* Wb   = (which == 0) ? Wqb : (which == 1) ? Wkb : Wvb;
    const float*  bias = (which == 0) ? bq  : (which == 1) ? bk  : bv;
    const float   oscale = (which == 0) ? 0.125f : 1.0f;

    const int f0 = tid, f1 = 256 + tid;
    const int rA0 = f0 >> 2, cA0 = (f0 & 3) * 8;
    const int rA1 = f1 >> 2, cA1 = (f1 & 3) * 8;
    int ga0 = m0 + rA0; if (ga0 > M_ - 1) ga0 = M_ - 1;
    int ga1 = m0 + rA1; if (ga1 > M_ - 1) ga1 = M_ - 1;
    const bf16_t* pA0 = Xb + (size_t)ga0 * H_ + cA0;
    const bf16_t* pA1 = Xb + (size_t)ga1 * H_ + cA1;
    const bf16_t* pB0 = Wb + (size_t)(nrel0 + rA0) * H_ + cA0;
    const bf16_t* pB1 = Wb + (size_t)(nrel0 + rA1) * H_ + cA1;
    bf16_t* lA0 = sA + w * 512;            // wave-uniform bases (+lane*16B by HW)
    bf16_t* lA1 = sA + 2048 + w * 512;
    bf16_t* lB0 = sB + w * 512;
    bf16_t* lB1 = sB + 2048 + w * 512;

    f32x4 acc[4][4] = {};
    for (int k0 = 0; k0 < H_; k0 += 32) {
        STAGE16(pA0 + k0, lA0);
        STAGE16(pA1 + k0, lA1);
        STAGE16(pB0 + k0, lB0);
        STAGE16(pB1 + k0, lB1);
        __syncthreads();
        bf16x8 af[4], bfv[4];
#pragma unroll
        for (int t = 0; t < 4; ++t) {
            af[t]  = load8(sA + (wm * 64 + t * 16 + l16) * 32 + quad * 8);
            bfv[t] = load8(sB + (wn * 64 + t * 16 + l16) * 32 + quad * 8);
        }
#pragma unroll
        for (int i = 0; i < 4; ++i)
#pragma unroll
            for (int j = 0; j < 4; ++j)
                acc[i][j] = __builtin_amdgcn_mfma_f32_16x16x32_bf16(af[i], bfv[j], acc[i][j], 0, 0, 0);
        __syncthreads();
    }

#pragma unroll
    for (int j = 0; j < 4; ++j) {
        const int nrel = nrel0 + wn * 64 + j * 16 + l16;
        const float bv_ = bias[nrel];
        const int h = nrel >> 6, d = nrel & 63;
#pragma unroll
        for (int i = 0; i < 4; ++i) {
#pragma unroll
            for (int r = 0; r < 4; ++r) {
                const int m = m0 + wm * 64 + i * 16 + quad * 4 + r;
                if (m >= M_) continue;
                const float val = (acc[i][j][r] + bv_) * oscale;
                const int b = m / S_, s = m - b * S_;
                const int bh = b * NH_ + h;
                if (which == 0)      Qb [((size_t)bh * S_ + s) * DH_ + d] = (bf16_t)val;
                else if (which == 1) Kb [((size_t)bh * S_ + s) * DH_ + d] = (bf16_t)val;
                else                 VTb[((size_t)bh * DH_ + d) * SP + s] = (bf16_t)val;
            }
        }
    }
}

// ---------------- flash attention, round 8: zero-shuffle ----------------
// grid (2560), block 256 (4 waves, each wave owns 32 q-rows = 2 MFMA tiles).
// XCD swizzle: bid%8 = XCD, 320 contiguous works per XCD -> each (b,h)'s 5
// blocks co-resident on one XCD (K/V ~152KB L2-resident; verified R7:
// FETCH 335->56MB).
// Swapped QK^T with PERMUTED K rows: A-frag row m is fed by lanes l16==m, so
// lane l16 loads K row g0=8*(l16>>2)+(l16&3) for score mfma #1 and g0+4 for
// mfma #2. Then lane (l16,quad) reg r holds S[q=l16][k=8*quad+r] (s0) and
// [k=8*quad+4+r] (s1) — i.e. after exp, this lane holds exactly the PV
// A-fragment element j=k-8*quad for k=8q..8q+7. P never touches LDS.
__global__ __launch_bounds__(256, 3) void flash_attn(
    const bf16_t* __restrict__ Qb, const bf16_t* __restrict__ Kb,
    const bf16_t* __restrict__ VTb, const float* __restrict__ maskp,
    bf16_t* __restrict__ Ctx)
{
    __shared__ __align__(16) float smask[SP];       // 2432B, zero-padded tail
    const int tid  = threadIdx.x;
    const int w    = tid >> 6, lane = tid & 63;
    const int quad = lane >> 4, l16 = lane & 15;

    const int bid  = blockIdx.x;
    const int work = (bid & 7) * 320 + (bid >> 3);  // bijective (2560%8==0)
    const int bh   = work / 5;
    const int qx   = work - bh * 5;
    const int b    = bh >> 4, h = bh & 15;

    for (int i = tid; i < SP; i += 256)
        smask[i] = (i < S_) ? maskp[b * S_ + i] : 0.f;
    __syncthreads();

    int idx = qx * 4 + w; if (idx > 18) idx = 18;   // dup work, same values
    const int q0 = idx * 32;

    const bf16_t* Qh = Qb  + (size_t)bh * S_ * DH_;
    const bf16_t* Kh = Kb  + (size_t)bh * S_ * DH_;
    const bf16_t* Vh = VTb + (size_t)bh * DH_ * SP;

    int rqA = q0 + l16;      if (rqA > S_ - 1) rqA = S_ - 1;
    int rqB = q0 + 16 + l16; if (rqB > S_ - 1) rqB = S_ - 1;
    const bf16x8 aqA0 = load8(Qh + rqA * DH_ + quad * 8);
    const bf16x8 aqA1 = load8(Qh + rqA * DH_ + 32 + quad * 8);
    const bf16x8 aqB0 = load8(Qh + rqB * DH_ + quad * 8);
    const bf16x8 aqB1 = load8(Qh + rqB * DH_ + 32 + quad * 8);

    const int g0 = ((l16 >> 2) << 3) + (l16 & 3);   // permuted K row (zero-shuffle)
    const int g1 = g0 + 4;

    f32x4 oA[4] = {}, oB[4] = {};
    float lpA = 0.f, lpB = 0.f;

    bf16x8 ka[4], kb_[4];
    {
        int r0 = g0; if (r0 > S_ - 1) r0 = S_ - 1;
        int r1 = g1; if (r1 > S_ - 1) r1 = S_ - 1;
        ka[0] = load8(Kh + r0 * DH_ + quad * 8);
        ka[1] = load8(Kh + r0 * DH_ + 32 + quad * 8);
        ka[2] = load8(Kh + r1 * DH_ + quad * 8);
        ka[3] = load8(Kh + r1 * DH_ + 32 + quad * 8);
    }

    auto body = [&](bf16x8 (&KC)[4], bf16x8 (&KN)[4], const int j0, const bool pf) {
        // V for this tile first (needed only after QK+exp -> latency hidden),
        // then K prefetch for next tile (needed a full body later).
        bf16x8 v0 = load8(Vh + (l16)      * SP + j0 + quad * 8);
        bf16x8 v1 = load8(Vh + (16 + l16) * SP + j0 + quad * 8);
        bf16x8 v2 = load8(Vh + (32 + l16) * SP + j0 + quad * 8);
        bf16x8 v3 = load8(Vh + (48 + l16) * SP + j0 + quad * 8);
        if (pf) {
            int r0 = j0 + 32 + g0; if (r0 > S_ - 1) r0 = S_ - 1;
            int r1 = j0 + 32 + g1; if (r1 > S_ - 1) r1 = S_ - 1;
            KN[0] = load8(Kh + r0 * DH_ + quad * 8);
            KN[1] = load8(Kh + r0 * DH_ + 32 + quad * 8);
            KN[2] = load8(Kh + r1 * DH_ + quad * 8);
            KN[3] = load8(Kh + r1 * DH_ + 32 + quad * 8);
        }
        // scores: lane (l16,quad) -> s*0[r] = S[q][j0+8*quad+r],
        //                            s*1[r] = S[q][j0+8*quad+4+r]
        f32x4 sA0 = {}, sA1 = {}, sB0 = {}, sB1 = {};
        sA0 = __builtin_amdgcn_mfma_f32_16x16x32_bf16(KC[0], aqA0, sA0, 0, 0, 0);
        sA0 = __builtin_amdgcn_mfma_f32_16x16x32_bf16(KC[1], aqA1, sA0, 0, 0, 0);
        sA1 = __builtin_amdgcn_mfma_f32_16x16x32_bf16(KC[2], aqA0, sA1, 0, 0, 0);
        sA1 = __builtin_amdgcn_mfma_f32_16x16x32_bf16(KC[3], aqA1, sA1, 0, 0, 0);
        sB0 = __builtin_amdgcn_mfma_f32_16x16x32_bf16(KC[0], aqB0, sB0, 0, 0, 0);
        sB0 = __builtin_amdgcn_mfma_f32_16x16x32_bf16(KC[1], aqB1, sB0, 0, 0, 0);
        sB1 = __builtin_amdgcn_mfma_f32_16x16x32_bf16(KC[2], aqB0, sB1, 0, 0, 0);
        sB1 = __builtin_amdgcn_mfma_f32_16x16x32_bf16(KC[3], aqB1, sB1, 0, 0, 0);

        const f32x4 mk0 = *reinterpret_cast<const f32x4*>(&smask[j0 + quad * 8]);
        const f32x4 mk1 = *reinterpret_cast<const f32x4*>(&smask[j0 + quad * 8 + 4]);
        bf16x8 apA, apB;
#pragma unroll
        for (int r = 0; r < 4; ++r) {
            const int c0 = j0 + quad * 8 + r;
            const int c1 = c0 + 4;
            const float eA0 = (c0 < S_) ? __expf(sA0[r] * mk0[r]) : 0.f;
            const float eA1 = (c1 < S_) ? __expf(sA1[r] * mk1[r]) : 0.f;
            const float eB0 = (c0 < S_) ? __expf(sB0[r] * mk0[r]) : 0.f;
            const float eB1 = (c1 < S_) ? __expf(sB1[r] * mk1[r]) : 0.f;
            lpA += eA0 + eA1;               // P=0 on pad cols kills V poison
            lpB += eB0 + eB1;
            apA[r] = (bf16_t)eA0; apA[r + 4] = (bf16_t)eA1;
            apB[r] = (bf16_t)eB0; apB[r + 4] = (bf16_t)eB1;
        }
        oA[0] = __builtin_amdgcn_mfma_f32_16x16x32_bf16(apA, v0, oA[0], 0, 0, 0);
        oB[0] = __builtin_amdgcn_mfma_f32_16x16x32_bf16(apB, v0, oB[0], 0, 0, 0);
        oA[1] = __builtin_amdgcn_mfma_f32_16x16x32_bf16(apA, v1, oA[1], 0, 0, 0);
        oB[1] = __builtin_amdgcn_mfma_f32_16x16x32_bf16(apB, v1, oB[1], 0, 0, 0);
        oA[2] = __builtin_amdgcn_mfma_f32_16x16x32_bf16(apA, v2, oA[2], 0, 0, 0);
        oB[2] = __builtin_amdgcn_mfma_f32_16x16x32_bf16(apB, v2, oB[2], 0, 0, 0);
        oA[3] = __builtin_amdgcn_mfma_f32_16x16x32_bf16(apA, v3, oA[3], 0, 0, 0);
        oB[3] = __builtin_amdgcn_mfma_f32_16x16x32_bf16(apB, v3, oB[3], 0, 0, 0);
    };

    for (int j0 = 0; j0 < S_; j0 += 64) {           // 19 bodies, ka/kb alternate
        body(ka, kb_, j0, j0 + 32 < S_);
        if (j0 + 32 < S_) body(kb_, ka, j0 + 32, j0 + 64 < S_);
    }

    // row sums: quads hold disjoint k-slices of row q=l16 -> reduce over quads
    float lsA = lpA, lsB = lpB;
    lsA += __shfl_xor(lsA, 16); lsA += __shfl_xor(lsA, 32);
    lsB += __shfl_xor(lsB, 16); lsB += __shfl_xor(lsB, 32);
    float livA[4], livB[4];
#pragma unroll
    for (int r = 0; r < 4; ++r) {
        livA[r] = 1.0f / __shfl(lsA, quad * 4 + r); // lanes 0..15 hold full sums
        livB[r] = 1.0f / __shfl(lsB, quad * 4 + r);
    }

#pragma unroll
    for (int t = 0; t < 4; ++t) {
#pragma unroll
        for (int r = 0; r < 4; ++r) {
            const int sA = q0 + quad * 4 + r;
            const int sB = sA + 16;
            if (sA < S_)
                Ctx[((size_t)(b * S_ + sA) * NH_ + h) * DH_ + t * 16 + l16] =
                    (bf16_t)(oA[t][r] * livA[r]);
            if (sB < S_)
                Ctx[((size_t)(b * S_ + sB) * NH_ + h) * DH_ + t * 16 + l16] =
                    (bf16_t)(oB[t][r] * livB[r]);
        }
    }
}

// ---------------- output projection, m97 structure. FP32 out ----------------
// grid (145, 8), block 256
__global__ __launch_bounds__(256) void out_gemm(
    const bf16_t* __restrict__ Ctx, const bf16_t* __restrict__ Wob,
    const float* __restrict__ bo, float* __restrict__ Out)
{
    __shared__ bf16_t smem[8192];
    bf16_t* sA = smem;
    bf16_t* sB = smem + 4096;
    const int tid  = threadIdx.x;
    const int w    = tid >> 6, lane = tid & 63;
    const int quad = lane >> 4, l16 = lane & 15;
    const int wm = w & 1, wn = w >> 1;
    const int m0 = blockIdx.x * 128, n0 = blockIdx.y * 128;

    const int f0 = tid, f1 = 256 + tid;
    const int rA0 = f0 >> 2, cA0 = (f0 & 3) * 8;
    const int rA1 = f1 >> 2, cA1 = (f1 & 3) * 8;
    int ga0 = m0 + rA0; if (ga0 > M_ - 1) ga0 = M_ - 1;
    int ga1 = m0 + rA1; if (ga1 > M_ - 1) ga1 = M_ - 1;
    const bf16_t* pA0 = Ctx + (size_t)ga0 * H_ + cA0;
    const bf16_t* pA1 = Ctx + (size_t)ga1 * H_ + cA1;
    const bf16_t* pB0 = Wob + (size_t)(n0 + rA0) * H_ + cA0;
    const bf16_t* pB1 = Wob + (size_t)(n0 + rA1) * H_ + cA1;
    bf16_t* lA0 = sA + w * 512;
    bf16_t* lA1 = sA + 2048 + w * 512;
    bf16_t* lB0 = sB + w * 512;
    bf16_t* lB1 = sB + 2048 + w * 512;

    f32x4 acc[4][4] = {};
    for (int k0 = 0; k0 < H_; k0 += 32) {
        STAGE16(pA0 + k0, lA0);
        STAGE16(pA1 + k0, lA1);
        STAGE16(pB0 + k0, lB0);
        STAGE16(pB1 + k0, lB1);
        __syncthreads();
        bf16x8 af[4], bfv[4];
#pragma unroll
        for (int t = 0; t < 4; ++t) {
            af[t]  = load8(sA + (wm * 64 + t * 16 + l16) * 32 + quad * 8);
            bfv[t] = load8(sB + (wn * 64 + t * 16 + l16) * 32 + quad * 8);
        }
#pragma unroll
        for (int i = 0; i < 4; ++i)
#pragma unroll
            for (int j = 0; j < 4; ++j)
                acc[i][j] = __builtin_amdgcn_mfma_f32_16x16x32_bf16(af[i], bfv[j], acc[i][j], 0, 0, 0);
        __syncthreads();
    }

#pragma unroll
    for (int j = 0; j < 4; ++j) {
        const int n = n0 + wn * 64 + j * 16 + l16;
        const float bv_ = bo[n];
#pragma unroll
        for (int i = 0; i < 4; ++i) {
#pragma unroll
            for (int r = 0; r < 4; ++r) {
                const int m = m0 + wm * 64 + i * 16 + quad * 4 + r;
                if (m >= M_) continue;
                Out[(size_t)m * H_ + n] = acc[i][j][r] + bv_;
            }
        }
    }
}

extern "C" void kernel_launch(void* const* d_in, const int* in_sizes, int n_in,
                              void* d_out, int out_size, void* d_ws, size_t ws_size,
                              hipStream_t stream) {
    const float* hidden = (const float*)d_in[0];
    const float* mask   = (const float*)d_in[1];
    const float* Wq = (const float*)d_in[2];
    const float* bq = (const float*)d_in[3];
    const float* Wk = (const float*)d_in[4];
    const float* bk = (const float*)d_in[5];
    const float* Wv = (const float*)d_in[6];
    const float* bv = (const float*)d_in[7];
    const float* Wo = (const float*)d_in[8];
    const float* bo = (const float*)d_in[9];
    float* out = (float*)d_out;

    const size_t QK_EL = (size_t)B_ * NH_ * S_ * DH_;   // 18,907,136
    const size_t VT_EL = (size_t)B_ * NH_ * SP * DH_;   // 19,922,944
    const size_t X_EL  = (size_t)M_ * H_;               // 18,907,136
    const size_t W_EL  = (size_t)H_ * H_;               // 1,048,576
    const size_t NEED  = (2 * QK_EL + VT_EL + X_EL + 4 * W_EL) * sizeof(bf16_t); // ~161.7 MB
    if (ws_size < NEED) {
        hipMemsetAsync(d_out, 0, (size_t)out_size * sizeof(float), stream);
        return;
    }

    bf16_t* ws    = (bf16_t*)d_ws;
    bf16_t* Qb    = ws;
    bf16_t* Kb    = Qb + QK_EL;
    bf16_t* VTb   = Kb + QK_EL;
    bf16_t* XbCtx = VTb + VT_EL;      // X_bf16 during qkv; Ctx afterwards
    bf16_t* Wqb   = XbCtx + X_EL;
    bf16_t* Wkb   = Wqb + W_EL;
    bf16_t* Wvb   = Wkb + W_EL;
    bf16_t* Wob   = Wvb + W_EL;

    cvt_f32_bf16<<<2048, 256, 0, stream>>>(hidden, XbCtx, (int)(X_EL / 8));
    cvt_w4<<<2048, 256, 0, stream>>>(Wq, Wk, Wv, Wo, Wqb);   // Wqb..Wob contiguous

    dim3 g1((M_ + 127) / 128, (3 * H_) / 128);   // 145 x 24
    qkv_gemm<<<g1, dim3(256), 0, stream>>>(XbCtx, Wqb, Wkb, Wvb, bq, bk, bv, Qb, Kb, VTb);

    flash_attn<<<dim3(2560), dim3(256), 0, stream>>>(Qb, Kb, VTb, mask, XbCtx);  // Ctx aliases Xb

    dim3 g3((M_ + 127) / 128, H_ / 128);         // 145 x 8
    out_gemm<<<g3, dim3(256), 0, stream>>>(XbCtx, Wob, bo, out);
}

// Round 3
// 504.859 us; speedup vs baseline: 1.4605x; 1.1925x over previous
//
#include <hip/hip_runtime.h>
#include <hip/hip_bf16.h>

// B=32, S=577, H=1024, NH=16, DH=64. fp32 inputs / fp32 OUTPUT.
// Round 9: GEMM traffic + epilogue attack. R8 counters: qkv_gemm 258us is
// the top kernel (MfmaUtil 19%, FETCH 476MB vs ~45 ideal, WRITE 200MB with
// 2B-scattered Q/K stores). Changes:
//  (1) slab-swizzled 1-D grids for qkv/out: 8-m-tile slabs (2MB of X, fits
//      XCD L2) swept n-fast, contiguous chunk per XCD -> A fetched ~once,
//      staging becomes L2-hit -> smaller vmcnt(0) drain per K-step.
//  (2) Q/K blocks swap MFMA operands (mfma(B,A)) so reg r runs along d:
//      epilogue = one bf16x4 (8B) store per (i,j); V keeps normal order
//      (r runs along s = VT contiguous axis) and packs bf16x4 too.
//  (3) out_gemm swapped + f32x4 (16B) coalesced stores + slab swizzle.
// flash_attn unchanged from R8 (zero-shuffle, ~150us).

typedef __bf16 bf16_t;
typedef __bf16 bf16x8 __attribute__((ext_vector_type(8)));
typedef __bf16 bf16x4 __attribute__((ext_vector_type(4)));
typedef float f32x4 __attribute__((ext_vector_type(4)));

#define B_   32
#define S_   577
#define SP   608
#define H_   1024
#define NH_  16
#define DH_  64
#define M_   (B_ * S_)    // 18464

typedef __attribute__((address_space(3))) unsigned int lds_u32;
typedef const __attribute__((address_space(1))) unsigned int glb_u32;
#define STAGE16(gp, lp) __builtin_amdgcn_global_load_lds((glb_u32*)(gp), (lds_u32*)(lp), 16, 0, 0)

__device__ __forceinline__ bf16x8 load8(const bf16_t* p) {
    return *reinterpret_cast<const bf16x8*>(p);
}
__device__ __forceinline__ bf16x8 load8f(const float* p) {
    f32x4 a = *reinterpret_cast<const f32x4*>(p);
    f32x4 b = *reinterpret_cast<const f32x4*>(p + 4);
    bf16x8 r;
    r[0] = (bf16_t)a[0]; r[1] = (bf16_t)a[1]; r[2] = (bf16_t)a[2]; r[3] = (bf16_t)a[3];
    r[4] = (bf16_t)b[0]; r[5] = (bf16_t)b[1]; r[6] = (bf16_t)b[2]; r[7] = (bf16_t)b[3];
    return r;
}

// ---------------- fp32 -> bf16 convert ----------------
__global__ __launch_bounds__(256) void cvt_f32_bf16(const float* __restrict__ src,
                                                    bf16_t* __restrict__ dst, int n8)
{
    int i = blockIdx.x * blockDim.x + threadIdx.x;
    const int stride = gridDim.x * blockDim.x;
    for (; i < n8; i += stride)
        *reinterpret_cast<bf16x8*>(dst + (size_t)i * 8) = load8f(src + (size_t)i * 8);
}

// all four weights in one launch; dsts are contiguous (Wqb..Wob in ws).
__global__ __launch_bounds__(256) void cvt_w4(
    const float* __restrict__ s0, const float* __restrict__ s1,
    const float* __restrict__ s2, const float* __restrict__ s3,
    bf16_t* __restrict__ dst)
{
    const int i = blockIdx.x * blockDim.x + threadIdx.x;   // 0..524287 (4*131072)
    const int which = i >> 17;                             // uniform per block
    const int off = i & ((1 << 17) - 1);
    const float* s = (which == 0) ? s0 : (which == 1) ? s1 : (which == 2) ? s2 : s3;
    *reinterpret_cast<bf16x8*>(dst + (size_t)i * 8) = load8f(s + (size_t)off * 8);
}

// shared m97 main loop. SWAP=1: acc[i][j] = mfma(bfv[j], af[i]) -> reg r
// runs along n (l16 = m row). SWAP=0: normal (r along m, l16 = n).
#define GEMM_MAINLOOP(SWAP)                                                      \
    for (int k0 = 0; k0 < H_; k0 += 32) {                                        \
        STAGE16(pA0 + k0, lA0);                                                  \
        STAGE16(pA1 + k0, lA1);                                                  \
        STAGE16(pB0 + k0, lB0);                                                  \
        STAGE16(pB1 + k0, lB1);                                                  \
        __syncthreads();                                                         \
        bf16x8 af[4], bfv[4];                                                    \
        _Pragma("unroll")                                                        \
        for (int tt = 0; tt < 4; ++tt) {                                         \
            af[tt]  = load8(sA + (wm * 64 + tt * 16 + l16) * 32 + quad * 8);     \
            bfv[tt] = load8(sB + (wn * 64 + tt * 16 + l16) * 32 + quad * 8);     \
        }                                                                        \
        _Pragma("unroll")                                                        \
        for (int i = 0; i < 4; ++i)                                              \
            _Pragma("unroll")                                                    \
            for (int j = 0; j < 4; ++j)                                          \
                acc[i][j] = (SWAP)                                               \
                    ? __builtin_amdgcn_mfma_f32_16x16x32_bf16(bfv[j], af[i], acc[i][j], 0, 0, 0) \
                    : __builtin_amdgcn_mfma_f32_16x16x32_bf16(af[i], bfv[j], acc[i][j], 0, 0, 0); \
        __syncthreads();                                                         \
    }

// ---------------- fused QKV projection ----------------
// 1-D grid 3480 = 145 m-tiles x 24 n-tiles. Work order: 8-m-tile slabs,
// n-fast within slab; contiguous 435-work chunk per XCD (bid%8).
__global__ __launch_bounds__(256) void qkv_gemm(
    const bf16_t* __restrict__ Xb,
    const bf16_t* __restrict__ Wqb, const bf16_t* __restrict__ Wkb, const bf16_t* __restrict__ Wvb,
    const float* __restrict__ bq, const float* __restrict__ bk, const float* __restrict__ bv,
    bf16_t* __restrict__ Qb, bf16_t* __restrict__ Kb, bf16_t* __restrict__ VTb)
{
    __shared__ bf16_t smem[8192];          // A[128][32] | B[128][32], contiguous (no pad!)
    bf16_t* sA = smem;
    bf16_t* sB = smem + 4096;
    const int tid  = threadIdx.x;
    const int w    = tid >> 6, lane = tid & 63;
    const int quad = lane >> 4, l16 = lane & 15;
    const int wm = w & 1, wn = w >> 1;

    const int t    = (blockIdx.x & 7) * 435 + (blockIdx.x >> 3);  // bijective, 3480%8==0
    const int slab = t / 192;                                     // 8 m-tiles x 24 n = 192
    const int rem  = t - slab * 192;
    int mt, nt;
    if (slab < 18) { nt = rem >> 3; mt = slab * 8 + (rem & 7); }
    else           { nt = rem;      mt = 144; }                   // last partial slab
    const int m0 = mt * 128, n0 = nt * 128;

    const int which = n0 >> 10;            // 128-tile never straddles a weight boundary
    const int nrel0 = n0 & 1023;
    const bf16_t* Wb   = (which == 0) ? Wqb : (which == 1) ? Wkb : Wvb;
    const float*  bias = (which == 0) ? bq  : (which == 1) ? bk  : bv;
    const float   oscale = (which == 0) ? 0.125f : 1.0f;

    const int f0 = tid, f1 = 256 + tid;
    const int rA0 = f0 >> 2, cA0 = (f0 & 3) * 8;
    const int rA1 = f1 >> 2, cA1 = (f1 & 3) * 8;
    int ga0 = m0 + rA0; if (ga0 > M_ - 1) ga0 = M_ - 1;
    int ga1 = m0 + rA1; if (ga1 > M_ - 1) ga1 = M_ - 1;
    const bf16_t* pA0 = Xb + (size_t)ga0 * H_ + cA0;
    const bf16_t* pA1 = Xb + (size_t)ga1 * H_ + cA1;
    const bf16_t* pB0 = Wb + (size_t)(nrel0 + rA0) * H_ + cA0;
    const bf16_t* pB1 = Wb + (size_t)(nrel0 + rA1) * H_ + cA1;
    bf16_t* lA0 = sA + w * 512;            // wave-uniform bases (+lane*16B by HW)
    bf16_t* lA1 = sA + 2048 + w * 512;
    bf16_t* lB0 = sB + w * 512;
    bf16_t* lB1 = sB + 2048 + w * 512;

    f32x4 acc[4][4] = {};
    if (which != 2) {
        GEMM_MAINLOOP(1)
        // swapped: (i,j) tile -> m = m0+wm*64+i*16+l16, n-run = 16*(wn*4+j)+quad*4+r
        bf16_t* QKout = (which == 0) ? Qb : Kb;
#pragma unroll
        for (int j = 0; j < 4; ++j) {
            const int u  = wn * 4 + j;                 // 16-col unit
            const int h  = (nrel0 >> 6) + (u >> 2);
            const int d0 = (u & 3) * 16 + quad * 4;
            const f32x4 b4 = *reinterpret_cast<const f32x4*>(&bias[nrel0 + u * 16 + quad * 4]);
#pragma unroll
            for (int i = 0; i < 4; ++i) {
                const int m = m0 + wm * 64 + i * 16 + l16;
                if (m >= M_) continue;
                const int b = m / S_, s = m - b * S_;
                const int bh = b * NH_ + h;
                bf16x4 pk;
#pragma unroll
                for (int r = 0; r < 4; ++r) pk[r] = (bf16_t)((acc[i][j][r] + b4[r]) * oscale);
                *reinterpret_cast<bf16x4*>(QKout + ((size_t)bh * S_ + s) * DH_ + d0) = pk;
            }
        }
    } else {
        GEMM_MAINLOOP(0)
        // normal: (i,j) tile -> d from l16, s-run = m0+wm*64+i*16+quad*4+r
#pragma unroll
        for (int j = 0; j < 4; ++j) {
            const int nrel = nrel0 + wn * 64 + j * 16 + l16;
            const float bv_ = bias[nrel];
            const int h = nrel >> 6, d = nrel & 63;
#pragma unroll
            for (int i = 0; i < 4; ++i) {
                const int m = m0 + wm * 64 + i * 16 + quad * 4;
                const int b = m / S_, s = m - b * S_;
                if (m + 3 < M_ && s <= S_ - 4) {       // 4-run stays in one batch row
                    bf16x4 pk;
#pragma unroll
                    for (int r = 0; r < 4; ++r) pk[r] = (bf16_t)(acc[i][j][r] + bv_);
                    *reinterpret_cast<bf16x4*>(VTb + ((size_t)(b * NH_ + h) * DH_ + d) * SP + s) = pk;
                } else {
#pragma unroll
                    for (int r = 0; r < 4; ++r) {
                        const int mm = m + r;
                        if (mm >= M_) continue;
                        const int bb = mm / S_, ss = mm - bb * S_;
                        VTb[((size_t)(bb * NH_ + h) * DH_ + d) * SP + ss] = (bf16_t)(acc[i][j][r] + bv_);
                    }
                }
            }
        }
    }
}

// ---------------- flash attention, round 8: zero-shuffle (unchanged) ----------------
__global__ __launch_bounds__(256, 3) void flash_attn(
    const bf16_t* __restrict__ Qb, const bf16_t* __restrict__ Kb,
    const bf16_t* __restrict__ VTb, const float* __restrict__ maskp,
    bf16_t* __restrict__ Ctx)
{
    __shared__ __align__(16) float smask[SP];       // 2432B, zero-padded tail
    const int tid  = threadIdx.x;
    const int w    = tid >> 6, lane = tid & 63;
    const int quad = lane >> 4, l16 = lane & 15;

    const int bid  = blockIdx.x;
    const int work = (bid & 7) * 320 + (bid >> 3);  // bijective (2560%8==0)
    const int bh   = work / 5;
    const int qx   = work - bh * 5;
    const int b    = bh >> 4, h = bh & 15;

    for (int i = tid; i < SP; i += 256)
        smask[i] = (i < S_) ? maskp[b * S_ + i] : 0.f;
    __syncthreads();

    int idx = qx * 4 + w; if (idx > 18) idx = 18;   // dup work, same values
    const int q0 = idx * 32;

    const bf16_t* Qh = Qb  + (size_t)bh * S_ * DH_;
    const bf16_t* Kh = Kb  + (size_t)bh * S_ * DH_;
    const bf16_t* Vh = VTb + (size_t)bh * DH_ * SP;

    int rqA = q0 + l16;      if (rqA > S_ - 1) rqA = S_ - 1;
    int rqB = q0 + 16 + l16; if (rqB > S_ - 1) rqB = S_ - 1;
    const bf16x8 aqA0 = load8(Qh + rqA * DH_ + quad * 8);
    const bf16x8 aqA1 = load8(Qh + rqA * DH_ + 32 + quad * 8);
    const bf16x8 aqB0 = load8(Qh + rqB * DH_ + quad * 8);
    const bf16x8 aqB1 = load8(Qh + rqB * DH_ + 32 + quad * 8);

    const int g0 = ((l16 >> 2) << 3) + (l16 & 3);   // permuted K row (zero-shuffle)
    const int g1 = g0 + 4;

    f32x4 oA[4] = {}, oB[4] = {};
    float lpA = 0.f, lpB = 0.f;

    bf16x8 ka[4], kb_[4];
    {
        int r0 = g0; if (r0 > S_ - 1) r0 = S_ - 1;
        int r1 = g1; if (r1 > S_ - 1) r1 = S_ - 1;
        ka[0] = load8(Kh + r0 * DH_ + quad * 8);
        ka[1] = load8(Kh + r0 * DH_ + 32 + quad * 8);
        ka[2] = load8(Kh + r1 * DH_ + quad * 8);
        ka[3] = load8(Kh + r1 * DH_ + 32 + quad * 8);
    }

    auto body = [&](bf16x8 (&KC)[4], bf16x8 (&KN)[4], const int j0, const bool pf) {
        bf16x8 v0 = load8(Vh + (l16)      * SP + j0 + quad * 8);
        bf16x8 v1 = load8(Vh + (16 + l16) * SP + j0 + quad * 8);
        bf16x8 v2 = load8(Vh + (32 + l16) * SP + j0 + quad * 8);
        bf16x8 v3 = load8(Vh + (48 + l16) * SP + j0 + quad * 8);
        if (pf) {
            int r0 = j0 + 32 + g0; if (r0 > S_ - 1) r0 = S_ - 1;
            int r1 = j0 + 32 + g1; if (r1 > S_ - 1) r1 = S_ - 1;
            KN[0] = load8(Kh + r0 * DH_ + quad * 8);
            KN[1] = load8(Kh + r0 * DH_ + 32 + quad * 8);
            KN[2] = load8(Kh + r1 * DH_ + quad * 8);
            KN[3] = load8(Kh + r1 * DH_ + 32 + quad * 8);
        }
        f32x4 sA0 = {}, sA1 = {}, sB0 = {}, sB1 = {};
        sA0 = __builtin_amdgcn_mfma_f32_16x16x32_bf16(KC[0], aqA0, sA0, 0, 0, 0);
        sA0 = __builtin_amdgcn_mfma_f32_16x16x32_bf16(KC[1], aqA1, sA0, 0, 0, 0);
        sA1 = __builtin_amdgcn_mfma_f32_16x16x32_bf16(KC[2], aqA0, sA1, 0, 0, 0);
        sA1 = __builtin_amdgcn_mfma_f32_16x16x32_bf16(KC[3], aqA1, sA1, 0, 0, 0);
        sB0 = __builtin_amdgcn_mfma_f32_16x16x32_bf16(KC[0], aqB0, sB0, 0, 0, 0);
        sB0 = __builtin_amdgcn_mfma_f32_16x16x32_bf16(KC[1], aqB1, sB0, 0, 0, 0);
        sB1 = __builtin_amdgcn_mfma_f32_16x16x32_bf16(KC[2], aqB0, sB1, 0, 0, 0);
        sB1 = __builtin_amdgcn_mfma_f32_16x16x32_bf16(KC[3], aqB1, sB1, 0, 0, 0);

        const f32x4 mk0 = *reinterpret_cast<const f32x4*>(&smask[j0 + quad * 8]);
        const f32x4 mk1 = *reinterpret_cast<const f32x4*>(&smask[j0 + quad * 8 + 4]);
        bf16x8 apA, apB;
#pragma unroll
        for (int r = 0; r < 4; ++r) {
            const int c0 = j0 + quad * 8 + r;
            const int c1 = c0 + 4;
            const float eA0 = (c0 < S_) ? __expf(sA0[r] * mk0[r]) : 0.f;
            const float eA1 = (c1 < S_) ? __expf(sA1[r] * mk1[r]) : 0.f;
            const float eB0 = (c0 < S_) ? __expf(sB0[r] * mk0[r]) : 0.f;
            const float eB1 = (c1 < S_) ? __expf(sB1[r] * mk1[r]) : 0.f;
            lpA += eA0 + eA1;               // P=0 on pad cols kills V poison
            lpB += eB0 + eB1;
            apA[r] = (bf16_t)eA0; apA[r + 4] = (bf16_t)eA1;
            apB[r] = (bf16_t)eB0; apB[r + 4] = (bf16_t)eB1;
        }
        oA[0] = __builtin_amdgcn_mfma_f32_16x16x32_bf16(apA, v0, oA[0], 0, 0, 0);
        oB[0] = __builtin_amdgcn_mfma_f32_16x16x32_bf16(apB, v0, oB[0], 0, 0, 0);
        oA[1] = __builtin_amdgcn_mfma_f32_16x16x32_bf16(apA, v1, oA[1], 0, 0, 0);
        oB[1] = __builtin_amdgcn_mfma_f32_16x16x32_bf16(apB, v1, oB[1], 0, 0, 0);
        oA[2] = __builtin_amdgcn_mfma_f32_16x16x32_bf16(apA, v2, oA[2], 0, 0, 0);
        oB[2] = __builtin_amdgcn_mfma_f32_16x16x32_bf16(apB, v2, oB[2], 0, 0, 0);
        oA[3] = __builtin_amdgcn_mfma_f32_16x16x32_bf16(apA, v3, oA[3], 0, 0, 0);
        oB[3] = __builtin_amdgcn_mfma_f32_16x16x32_bf16(apB, v3, oB[3], 0, 0, 0);
    };

    for (int j0 = 0; j0 < S_; j0 += 64) {           // 19 bodies, ka/kb alternate
        body(ka, kb_, j0, j0 + 32 < S_);
        if (j0 + 32 < S_) body(kb_, ka, j0 + 32, j0 + 64 < S_);
    }

    float lsA = lpA, lsB = lpB;
    lsA += __shfl_xor(lsA, 16); lsA += __shfl_xor(lsA, 32);
    lsB += __shfl_xor(lsB, 16); lsB += __shfl_xor(lsB, 32);
    float livA[4], livB[4];
#pragma unroll
    for (int r = 0; r < 4; ++r) {
        livA[r] = 1.0f / __shfl(lsA, quad * 4 + r); // lanes 0..15 hold full sums
        livB[r] = 1.0f / __shfl(lsB, quad * 4 + r);
    }

#pragma unroll
    for (int t = 0; t < 4; ++t) {
#pragma unroll
        for (int r = 0; r < 4; ++r) {
            const int sA = q0 + quad * 4 + r;
            const int sB = sA + 16;
            if (sA < S_)
                Ctx[((size_t)(b * S_ + sA) * NH_ + h) * DH_ + t * 16 + l16] =
                    (bf16_t)(oA[t][r] * livA[r]);
            if (sB < S_)
                Ctx[((size_t)(b * S_ + sB) * NH_ + h) * DH_ + t * 16 + l16] =
                    (bf16_t)(oB[t][r] * livB[r]);
        }
    }
}

// ---------------- output projection. FP32 out, swapped+coalesced ----------------
// 1-D grid 1160 = 145 m-tiles x 8 n-tiles, slab-swizzled like qkv.
__global__ __launch_bounds__(256) void out_gemm(
    const bf16_t* __restrict__ Ctx, const bf16_t* __restrict__ Wob,
    const float* __restrict__ bo, float* __restrict__ Out)
{
    __shared__ bf16_t smem[8192];
    bf16_t* sA = smem;
    bf16_t* sB = smem + 4096;
    const int tid  = threadIdx.x;
    const int w    = tid >> 6, lane = tid & 63;
    const int quad = lane >> 4, l16 = lane & 15;
    const int wm = w & 1, wn = w >> 1;

    const int t    = (blockIdx.x & 7) * 145 + (blockIdx.x >> 3);  // 1160%8==0
    const int slab = t / 64;                                      // 8 m x 8 n = 64
    const int rem  = t - slab * 64;
    int mt, nt;
    if (slab < 18) { nt = rem >> 3; mt = slab * 8 + (rem & 7); }
    else           { nt = rem;      mt = 144; }
    const int m0 = mt * 128, n0 = nt * 128;

    const int f0 = tid, f1 = 256 + tid;
    const int rA0 = f0 >> 2, cA0 = (f0 & 3) * 8;
    const int rA1 = f1 >> 2, cA1 = (f1 & 3) * 8;
    int ga0 = m0 + rA0; if (ga0 > M_ - 1) ga0 = M_ - 1;
    int ga1 = m0 + rA1; if (ga1 > M_ - 1) ga1 = M_ - 1;
    const bf16_t* pA0 = Ctx + (size_t)ga0 * H_ + cA0;
    const bf16_t* pA1 = Ctx + (size_t)ga1 * H_ + cA1;
    const bf16_t* pB0 = Wob + (size_t)(n0 + rA0) * H_ + cA0;
    const bf16_t* pB1 = Wob + (size_t)(n0 + rA1) * H_ + cA1;
    bf16_t* lA0 = sA + w * 512;
    bf16_t* lA1 = sA + 2048 + w * 512;
    bf16_t* lB0 = sB + w * 512;
    bf16_t* lB1 = sB + 2048 + w * 512;

    f32x4 acc[4][4] = {};
    GEMM_MAINLOOP(1)

    // swapped: m = m0+wm*64+i*16+l16, n-run = n0+wn*64+j*16+quad*4+{0..3}
#pragma unroll
    for (int j = 0; j < 4; ++j) {
        const int nb = n0 + wn * 64 + j * 16 + quad * 4;
        const f32x4 b4 = *reinterpret_cast<const f32x4*>(&bo[nb]);
#pragma unroll
        for (int i = 0; i < 4; ++i) {
            const int m = m0 + wm * 64 + i * 16 + l16;
            if (m >= M_) continue;
            f32x4 v = acc[i][j] + b4;
            *reinterpret_cast<f32x4*>(Out + (size_t)m * H_ + nb) = v;
        }
    }
}

extern "C" void kernel_launch(void* const* d_in, const int* in_sizes, int n_in,
                              void* d_out, int out_size, void* d_ws, size_t ws_size,
                              hipStream_t stream) {
    const float* hidden = (const float*)d_in[0];
    const float* mask   = (const float*)d_in[1];
    const float* Wq = (const float*)d_in[2];
    const float* bq = (const float*)d_in[3];
    const float* Wk = (const float*)d_in[4];
    const float* bk = (const float*)d_in[5];
    const float* Wv = (const float*)d_in[6];
    const float* bv = (const float*)d_in[7];
    const float* Wo = (const float*)d_in[8];
    const float* bo = (const float*)d_in[9];
    float* out = (float*)d_out;

    const size_t QK_EL = (size_t)B_ * NH_ * S_ * DH_;   // 18,907,136
    const size_t VT_EL = (size_t)B_ * NH_ * SP * DH_;   // 19,922,944
    const size_t X_EL  = (size_t)M_ * H_;               // 18,907,136
    const size_t W_EL  = (size_t)H_ * H_;               // 1,048,576
    const size_t NEED  = (2 * QK_EL + VT_EL + X_EL + 4 * W_EL) * sizeof(bf16_t); // ~161.7 MB
    if (ws_size < NEED) {
        hipMemsetAsync(d_out, 0, (size_t)out_size * sizeof(float), stream);
        return;
    }

    bf16_t* ws    = (bf16_t*)d_ws;
    bf16_t* Qb    = ws;
    bf16_t* Kb    = Qb + QK_EL;
    bf16_t* VTb   = Kb + QK_EL;
    bf16_t* XbCtx = VTb + VT_EL;      // X_bf16 during qkv; Ctx afterwards
    bf16_t* Wqb   = XbCtx + X_EL;
    bf16_t* Wkb   = Wqb + W_EL;
    bf16_t* Wvb   = Wkb + W_EL;
    bf16_t* Wob   = Wvb + W_EL;

    cvt_f32_bf16<<<2048, 256, 0, stream>>>(hidden, XbCtx, (int)(X_EL / 8));
    cvt_w4<<<2048, 256, 0, stream>>>(Wq, Wk, Wv, Wo, Wqb);   // Wqb..Wob contiguous

    qkv_gemm<<<dim3(3480), dim3(256), 0, stream>>>(XbCtx, Wqb, Wkb, Wvb, bq, bk, bv, Qb, Kb, VTb);

    flash_attn<<<dim3(2560), dim3(256), 0, stream>>>(Qb, Kb, VTb, mask, XbCtx);  // Ctx aliases Xb

    out_gemm<<<dim3(1160), dim3(256), 0, stream>>>(XbCtx, Wob, bo, out);
}